// Round 2
// baseline (1546.534 us; speedup 1.0000x reference)
//
#include <hip/hip_runtime.h>

#define F_IN 2
#define H 16
#define C 10
#define G_GRAPHS 1024
#define SCAN_BS 512   // elements + threads per scan1 block; nb must be <= 1024

// ---- degree histogram: deg[dst] += 1 ----
__global__ void k_deg(const int* __restrict__ dst, int* __restrict__ deg, int E) {
    int e = blockIdx.x * blockDim.x + threadIdx.x;
    if (e < E) atomicAdd(&deg[dst[e]], 1);
}

// ---- dis[n] = rsqrt(deg[n] + 1) ----
__global__ void k_dis(const int* __restrict__ deg, float* __restrict__ dis, int n) {
    int i = blockIdx.x * blockDim.x + threadIdx.x;
    if (i < n) dis[i] = rsqrtf((float)(deg[i] + 1));
}

// ---- scan phase 1: per-block exclusive scan of deg -> row_local, block sums -> bsum ----
__global__ void k_scan1(const int* __restrict__ deg, int* __restrict__ row_local,
                        int* __restrict__ bsum, int n) {
    __shared__ int s[SCAN_BS];
    int tid = threadIdx.x;
    int i = blockIdx.x * SCAN_BS + tid;
    int v = (i < n) ? deg[i] : 0;
    s[tid] = v;
    __syncthreads();
    for (int off = 1; off < SCAN_BS; off <<= 1) {
        int t = (tid >= off) ? s[tid - off] : 0;
        __syncthreads();
        s[tid] += t;
        __syncthreads();
    }
    if (i < n) row_local[i] = s[tid] - v;          // exclusive
    if (tid == SCAN_BS - 1) bsum[blockIdx.x] = s[tid];
}

// ---- scan phase 2: single-block exclusive scan of block sums (nb <= 1024) ----
__global__ void k_scan2(const int* __restrict__ bsum, int* __restrict__ boff, int nb) {
    __shared__ int s[1024];
    int tid = threadIdx.x;
    int v = (tid < nb) ? bsum[tid] : 0;
    s[tid] = v;
    __syncthreads();
    for (int off = 1; off < 1024; off <<= 1) {
        int t = (tid >= off) ? s[tid - off] : 0;
        __syncthreads();
        s[tid] += t;
        __syncthreads();
    }
    if (tid < nb) boff[tid] = s[tid] - v;          // exclusive
}

// ---- scan phase 3: row_start = row_local + boff[block]; cursor = row_start ----
__global__ void k_scan3(const int* __restrict__ row_local, const int* __restrict__ boff,
                        int* __restrict__ row_start, int* __restrict__ cursor, int n) {
    int i = blockIdx.x * blockDim.x + threadIdx.x;
    if (i >= n) return;
    int rs = row_local[i] + boff[i / SCAN_BS];
    row_start[i] = rs;
    cursor[i] = rs;
}

// ---- CSR fill: csr_src[slot] = src for each edge, slot via per-dst cursor ----
__global__ void k_fill(const int* __restrict__ src, const int* __restrict__ dst,
                       int* __restrict__ cursor, int* __restrict__ csr, int E) {
    int e = blockIdx.x * blockDim.x + threadIdx.x;
    if (e >= E) return;
    int slot = atomicAdd(&cursor[dst[e]], 1);
    csr[slot] = src[e];
}

// ---- layer-1 linear: B[n][j] = (x[n][0]*W1[0][j] + x[n][1]*W1[1][j]) * dis[n] ----
__global__ void k_lin1(const float* __restrict__ x, const float* __restrict__ W1,
                       const float* __restrict__ dis, float* __restrict__ B, int n) {
    int i = blockIdx.x * blockDim.x + threadIdx.x;
    if (i >= n * H) return;
    int node = i >> 4, j = i & 15;
    float v = x[node * 2 + 0] * W1[j] + x[node * 2 + 1] * W1[H + j];
    B[i] = v * dis[node];
}

// ---- gather1: agg + epilogue(relu) + @W2*dis, B -> A.  16 lanes per node. ----
__global__ void k_gather1(const int* __restrict__ row_start, const int* __restrict__ deg,
                          const int* __restrict__ csr, const float* __restrict__ B,
                          const float* __restrict__ dis, const float* __restrict__ b1,
                          const float* __restrict__ W2, float* __restrict__ A, int n) {
    __shared__ float w2s[H * H];
    __shared__ float b1s[H];
    int tid = threadIdx.x;
    if (tid < H * H) w2s[tid] = W2[tid];
    if (tid < H) b1s[tid] = b1[tid];
    __syncthreads();
    int node = blockIdx.x * (blockDim.x / H) + (tid >> 4);
    int j = tid & 15;
    if (node >= n) return;
    int st = row_start[node];
    int d = deg[node];
    float acc = 0.0f;
    int k = 0;
    for (; k + 4 <= d; k += 4) {
        int s0 = csr[st + k], s1 = csr[st + k + 1], s2 = csr[st + k + 2], s3 = csr[st + k + 3];
        float v0 = B[s0 * H + j], v1 = B[s1 * H + j], v2 = B[s2 * H + j], v3 = B[s3 * H + j];
        acc += (v0 + v1) + (v2 + v3);
    }
    for (; k < d; k++) acc += B[csr[st + k] * H + j];
    float dn = dis[node];
    float h1 = fmaxf(dn * (acc + B[node * H + j]) + b1s[j], 0.0f);  // layer-1 out
    // hs2[j] = dis * sum_k h1[k] * W2[k][j]  (cross-lane within 16-lane group)
    float acc2 = 0.0f;
#pragma unroll
    for (int kk = 0; kk < H; kk++) acc2 += __shfl(h1, kk, H) * w2s[kk * H + j];
    A[node * H + j] = acc2 * dn;
}

// ---- gather2: agg + epilogue(relu) + pool atomicMax.  A -> pooled. ----
__global__ void k_gather2(const int* __restrict__ row_start, const int* __restrict__ deg,
                          const int* __restrict__ csr, const float* __restrict__ A,
                          const float* __restrict__ dis, const float* __restrict__ b2,
                          const int* __restrict__ batch, float* __restrict__ pooled, int n) {
    __shared__ float b2s[H];
    int tid = threadIdx.x;
    if (tid < H) b2s[tid] = b2[tid];
    __syncthreads();
    int node = blockIdx.x * (blockDim.x / H) + (tid >> 4);
    int j = tid & 15;
    if (node >= n) return;
    int st = row_start[node];
    int d = deg[node];
    float acc = 0.0f;
    int k = 0;
    for (; k + 4 <= d; k += 4) {
        int s0 = csr[st + k], s1 = csr[st + k + 1], s2 = csr[st + k + 2], s3 = csr[st + k + 3];
        float v0 = A[s0 * H + j], v1 = A[s1 * H + j], v2 = A[s2 * H + j], v3 = A[s3 * H + j];
        acc += (v0 + v1) + (v2 + v3);
    }
    for (; k < d; k++) acc += A[csr[st + k] * H + j];
    float dn = dis[node];
    float h2 = fmaxf(dn * (acc + A[node * H + j]) + b2s[j], 0.0f);
    int g = batch[node];
    atomicMax((int*)&pooled[g * H + j], __float_as_int(h2));   // h2 >= 0, init 0
}

// ---- head: logits = pooled @ Wl + bl, then log_softmax ----
__global__ void k_head(const float* __restrict__ pooled, const float* __restrict__ Wl,
                       const float* __restrict__ bl, float* __restrict__ out) {
    __shared__ float w[H * C];
    __shared__ float b[C];
    int tid = threadIdx.x;
    if (tid < H * C) w[tid] = Wl[tid];
    if (tid < C) b[tid] = bl[tid];
    __syncthreads();
    int g = blockIdx.x * blockDim.x + tid;
    if (g >= G_GRAPHS) return;
    float p[H];
#pragma unroll
    for (int k = 0; k < H; k++) p[k] = fmaxf(pooled[g * H + k], 0.0f);
    float l[C];
    float m = -1e30f;
#pragma unroll
    for (int c = 0; c < C; c++) {
        float acc = b[c];
#pragma unroll
        for (int k = 0; k < H; k++) acc += p[k] * w[k * C + c];
        l[c] = acc;
        m = fmaxf(m, acc);
    }
    float s = 0.0f;
#pragma unroll
    for (int c = 0; c < C; c++) s += expf(l[c] - m);
    float lse = logf(s);
#pragma unroll
    for (int c = 0; c < C; c++) out[g * C + c] = l[c] - m - lse;
}

extern "C" void kernel_launch(void* const* d_in, const int* in_sizes, int n_in,
                              void* d_out, int out_size, void* d_ws, size_t ws_size,
                              hipStream_t stream) {
    const float* x    = (const float*)d_in[0];
    const int*   eidx = (const int*)d_in[1];
    const int*   batch= (const int*)d_in[2];
    const float* W1   = (const float*)d_in[3];
    const float* b1   = (const float*)d_in[4];
    const float* W2   = (const float*)d_in[5];
    const float* b2   = (const float*)d_in[6];
    const float* Wl   = (const float*)d_in[7];
    const float* bl   = (const float*)d_in[8];
    float* out = (float*)d_out;

    int N = in_sizes[0] / F_IN;
    int E = in_sizes[1] / 2;
    const int* src = eidx;
    const int* dst = eidx + E;

    size_t featBytes = (size_t)N * H * sizeof(float);   // 32 MB
    size_t nodeInts  = (size_t)N * sizeof(int);         // 2 MB
    char* ws = (char*)d_ws;
    float* A        = (float*)ws;                                   ws += featBytes;
    float* B        = (float*)ws;                                   ws += featBytes;
    int*   csr      = (int*)ws;                                     ws += (size_t)E * sizeof(int);
    float* dis      = (float*)ws;                                   ws += nodeInts;
    int*   deg      = (int*)ws;                                     ws += nodeInts;
    int*   row_loc  = (int*)ws;                                     ws += nodeInts;
    int*   row_start= (int*)ws;                                     ws += nodeInts;
    int*   cursor   = (int*)ws;                                     ws += nodeInts;
    int*   bsum     = (int*)ws;                                     ws += 1024 * sizeof(int);
    int*   boff     = (int*)ws;                                     ws += 1024 * sizeof(int);
    float* pooled   = (float*)ws;                                   ws += (size_t)G_GRAPHS * H * sizeof(float);

    const int BS = 256;
    int nb   = (N + SCAN_BS - 1) / SCAN_BS;            // 977 <= 1024
    int gN   = (N + BS - 1) / BS;
    int gE   = (E + BS - 1) / BS;
    int gNH  = (int)(((long)N * H + BS - 1) / BS);
    int gG   = (N + (BS / H) - 1) / (BS / H);          // gather: 16 nodes / block

    // ---- graph structure ----
    hipMemsetAsync(deg, 0, nodeInts, stream);
    k_deg  <<<gE, BS, 0, stream>>>(dst, deg, E);
    k_dis  <<<gN, BS, 0, stream>>>(deg, dis, N);
    k_scan1<<<nb, SCAN_BS, 0, stream>>>(deg, row_loc, bsum, N);
    k_scan2<<<1, 1024, 0, stream>>>(bsum, boff, nb);
    k_scan3<<<gN, BS, 0, stream>>>(row_loc, boff, row_start, cursor, N);
    k_fill <<<gE, BS, 0, stream>>>(src, dst, cursor, csr, E);

    // ---- layers ----
    k_lin1   <<<gNH, BS, 0, stream>>>(x, W1, dis, B, N);
    k_gather1<<<gG, BS, 0, stream>>>(row_start, deg, csr, B, dis, b1, W2, A, N);
    hipMemsetAsync(pooled, 0, (size_t)G_GRAPHS * H * sizeof(float), stream);
    k_gather2<<<gG, BS, 0, stream>>>(row_start, deg, csr, A, dis, b2, batch, pooled, N);

    // ---- head ----
    k_head<<<(G_GRAPHS + BS - 1) / BS, BS, 0, stream>>>(pooled, Wl, bl, out);
}